// Round 7
// baseline (556.578 us; speedup 1.0000x reference)
//
#include <hip/hip_runtime.h>

// ANI AEV (radial + angular), scatter-free output writes.
// v7: (a) angular phase-2 processes 2 triples/iter using all 64 lanes
// (shfl_xor cross-half exchange, collision-merged, conflict-free banks);
// (b) scatter_binned does 4 pairs/thread for 4x atomic-latency ILP.
// Carries v6: arad aliased on scr (31744 B/block), tri_off fused in.

constexpr int   NATOMS = 50000;
constexpr int   P      = 1000000;
constexpr int   PA     = 200000;
constexpr int   S      = 7;
constexpr int   NRBF   = 16;
constexpr float RC     = 0.51f;
constexpr float RMIN   = 0.08f;
constexpr float RCA    = 0.35f;
constexpr float RAMIN  = 0.08f;
constexpr int   NA     = 8;
constexpr int   NZ     = 4;
constexpr float ETA_R  = 1970.0f;
constexpr float ETA_A  = 1250.0f;
constexpr float ZETA   = 14.1f;
constexpr int   NPAIRS = 28;
constexpr int   SUB    = 32;
constexpr int   RAD_W  = S * NRBF;      // 112
constexpr int   ANG_W  = NPAIRS * SUB;  // 896
constexpr int   AEV    = RAD_W + ANG_W; // 1008

constexpr float RSTEP  = (RC  - RMIN ) / NRBF;
constexpr float ASTEP  = (RCA - RAMIN) / NA;
constexpr float PI_F   = 3.14159265358979f;

constexpr int   CAP    = 96;                 // per-atom bin capacity (mean 40)
constexpr float DPACK   = 65535.0f / 0.52f;  // d in [0,0.52) -> 16-bit fixed
constexpr float DUNPACK = 0.52f / 65535.0f;

constexpr int   APB    = 4;                  // atoms (waves) per block
constexpr int   PQ     = P / 4;              // 250000 pairs per chunk

// per-wave LDS layout (floats): A[32*33]=1056 | scr[64*13]=832 | rsc[96]
// arad[4*112]=448 is ALIASED onto scr[0..447] (radial phase only).
constexpr int   A_WORDS  = 32 * 33;
constexpr int   SC_WORDS = 64 * 13;
constexpr int   RS_WORDS = CAP;
constexpr int   WLDS     = A_WORDS + SC_WORDS + RS_WORDS;  // 1984 -> 31744 B/blk

constexpr int   CHUNK  = 1024;
constexpr int   NCHUNK = (NATOMS + CHUNK - 1) / CHUNK;

// ------- radial binning + angular pair packing + triple offsets (fused) -------
// 4 pairs per thread (strided chunks): 8 independent atomic chains -> ILP
// hides the global-atomic round-trip latency.

__global__ __launch_bounds__(256)
void scatter_binned_kernel(const int* __restrict__ pair_indices,
                           const int* __restrict__ atom_index,
                           const float* __restrict__ d_ij,
                           const float* __restrict__ r_ij,
                           int* __restrict__ cnt,
                           unsigned* __restrict__ bins,
                           float4* __restrict__ packed,
                           const int* __restrict__ central,
                           int* __restrict__ toff, int T) {
    int t = blockIdx.x * blockDim.x + threadIdx.x;

    // --- tri_off part (threads t < T) ---
    if (toff != nullptr && t < T) {
        int c = central[t];
        if (t == 0) {
            for (int a = 0; a <= c; ++a) toff[a] = 0;
        } else {
            int cp = central[t - 1];
            for (int a = cp + 1; a <= c; ++a) toff[a] = t;
        }
        if (t == T - 1) {
            for (int a = c + 1; a <= NATOMS; ++a) toff[a] = T;
        }
    }

    if (t >= PQ) return;
    const int p0 = t, p1 = t + PQ, p2 = t + 2 * PQ, p3 = t + 3 * PQ;

    // independent loads (coalesced streams per chunk)
    int i0 = pair_indices[p0], i1 = pair_indices[p1];
    int i2 = pair_indices[p2], i3 = pair_indices[p3];
    int j0 = pair_indices[P + p0], j1 = pair_indices[P + p1];
    int j2 = pair_indices[P + p2], j3 = pair_indices[P + p3];
    float d0 = d_ij[p0], d1 = d_ij[p1], d2 = d_ij[p2], d3 = d_ij[p3];
    int si0 = atom_index[i0], si1 = atom_index[i1];
    int si2 = atom_index[i2], si3 = atom_index[i3];
    int sj0 = atom_index[j0], sj1 = atom_index[j1];
    int sj2 = atom_index[j2], sj3 = atom_index[j3];

    // pack (only chunk 0 overlaps [0, PA))
    if (packed != nullptr && p0 < PA) {
        unsigned bits = ((unsigned)si0 << 3) | (unsigned)sj0;
        float4 v;
        v.x = r_ij[3 * p0    ];
        v.y = r_ij[3 * p0 + 1];
        v.z = r_ij[3 * p0 + 2];
        v.w = __uint_as_float(bits);
        packed[p0] = v;
    }

    unsigned b0 = ((unsigned)__float2uint_rn(d0 * DPACK)) << 16;
    unsigned b1 = ((unsigned)__float2uint_rn(d1 * DPACK)) << 16;
    unsigned b2 = ((unsigned)__float2uint_rn(d2 * DPACK)) << 16;
    unsigned b3 = ((unsigned)__float2uint_rn(d3 * DPACK)) << 16;

    // 8 independent atomic chains
    int q0 = atomicAdd(&cnt[i0], 1);
    int q1 = atomicAdd(&cnt[j0], 1);
    int q2 = atomicAdd(&cnt[i1], 1);
    int q3 = atomicAdd(&cnt[j1], 1);
    int q4 = atomicAdd(&cnt[i2], 1);
    int q5 = atomicAdd(&cnt[j2], 1);
    int q6 = atomicAdd(&cnt[i3], 1);
    int q7 = atomicAdd(&cnt[j3], 1);

    if (q0 < CAP) bins[(size_t)i0 * CAP + q0] = b0 | (unsigned)sj0;
    if (q1 < CAP) bins[(size_t)j0 * CAP + q1] = b0 | (unsigned)si0;
    if (q2 < CAP) bins[(size_t)i1 * CAP + q2] = b1 | (unsigned)sj1;
    if (q3 < CAP) bins[(size_t)j1 * CAP + q3] = b1 | (unsigned)si1;
    if (q4 < CAP) bins[(size_t)i2 * CAP + q4] = b2 | (unsigned)sj2;
    if (q5 < CAP) bins[(size_t)j2 * CAP + q5] = b2 | (unsigned)si2;
    if (q6 < CAP) bins[(size_t)i3 * CAP + q6] = b3 | (unsigned)sj3;
    if (q7 < CAP) bins[(size_t)j3 * CAP + q7] = b3 | (unsigned)si3;
}

// ---------------- v7 fused per-atom row build: NO atomics ----------------

__global__ __launch_bounds__(256)
void fused_rows2_kernel(const int* __restrict__ cnt,
                        const unsigned* __restrict__ bins,
                        const int* __restrict__ pidx12,
                        const int* __restrict__ sign12,
                        const int* __restrict__ toff,
                        const float4* __restrict__ packed,
                        float* __restrict__ out, int T) {
    __shared__ float lds[APB * WLDS];

    const int w    = threadIdx.x >> 6;
    const int lane = threadIdx.x & 63;
    const int a    = blockIdx.x * APB + w;   // grid sized exactly NATOMS/APB

    float* A    = lds + w * WLDS;            // [32][33] lane-private rows
    float* scr  = A + A_WORDS;               // [64][13] per-triple scalars
    float* rsc  = scr + SC_WORDS;            // [CAP] radial entries
    float* arad = scr;                       // [4][112] ALIAS (radial phase only)

    // zero angular accumulator (264 float4)
    float4* A4 = (float4*)A;
#pragma unroll
    for (int q = 0; q < 5; ++q) {
        int idx = q * 64 + lane;
        if (idx < A_WORDS / 4) A4[idx] = make_float4(0.f, 0.f, 0.f, 0.f);
    }
    // zero radial accumulator (448 = 7*64) -- lives in scr for now
#pragma unroll
    for (int q = 0; q < 7; ++q) arad[q * 64 + lane] = 0.0f;

    // triple range; issue first-chunk gathers early (hidden under radial)
    const int start = toff[a];
    const int end   = toff[a + 1];
    const int t0    = start + lane;
    int p0 = 0, p1 = 0, g0 = 1, g1 = 1;
    float4 pk0 = make_float4(1.f, 0.f, 0.f, 0.f);
    float4 pk1 = make_float4(1.f, 0.f, 0.f, 0.f);
    if (t0 < end) {
        p0 = pidx12[t0];
        p1 = pidx12[T + t0];
        g0 = sign12[t0];
        g1 = sign12[T + t0];
        pk0 = packed[p0];
        pk1 = packed[p1];
    }

    // ---- radial phase: 4 entries per pass, q-replicated LDS scatter ----
    const int n = min(cnt[a], CAP);
    const unsigned* b = bins + (size_t)a * CAP;
    if (lane < n)      rsc[lane]      = __uint_as_float(b[lane]);
    if (64 + lane < n) rsc[64 + lane] = __uint_as_float(b[64 + lane]);

    const int k  = lane & 15, qg = lane >> 4;
    const float muk = RMIN + k * RSTEP;
    float* arq = arad + qg * RAD_W;          // this q-group's region
    for (int e0 = 0; e0 < n; e0 += 4) {
        int e = e0 + qg;
        if (e < n) {
            unsigned u = __float_as_uint(rsc[e]);
            float d  = (float)(u >> 16) * DUNPACK;
            int   sp = (int)(u & 7u);
            float fc = (d < RC) ? (0.5f * __cosf((PI_F / RC) * d) + 0.5f) : 0.0f;
            float dd = d - muk;
            float rbf = 0.25f * __expf(-ETA_R * dd * dd) * fc;
            arq[sp * NRBF + k] += rbf;       // distinct (qg, sp, k) addresses
        }
    }
    float* o = out + (size_t)a * AEV;
    {
        float v = arad[lane] + arad[RAD_W + lane] + arad[2 * RAD_W + lane]
                + arad[3 * RAD_W + lane];
        o[lane] = v;
        if (lane < RAD_W - 64) {
            int e2 = 64 + lane;
            float v2 = arad[e2] + arad[RAD_W + e2] + arad[2 * RAD_W + e2]
                     + arad[3 * RAD_W + e2];
            o[e2] = v2;
        }
    }
    // radial done; scr free for angular scratch (wave-private, sequential)

    // ---- angular: phase-1 per-triple scalars -> phase-2 paired accumulate ----
    const float CZV[NZ] = { 0.92387953f,  0.38268343f, -0.38268343f, -0.92387953f };
    const float SZV[NZ] = { 0.38268343f,  0.92387953f,  0.92387953f,  0.38268343f };

    for (int base = start; base < end; base += 64) {
        int t = base + lane;
        bool act = t < end;
        if (base != start && act) {
            p0 = pidx12[t];
            p1 = pidx12[T + t];
            g0 = sign12[t];
            g1 = sign12[T + t];
            pk0 = packed[p0];
            pk1 = packed[p1];
        }
        if (act) {
            float v0x = pk0.x, v0y = pk0.y, v0z = pk0.z;
            float v1x = pk1.x, v1y = pk1.y, v1z = pk1.z;
            unsigned b0 = __float_as_uint(pk0.w);
            unsigned b1 = __float_as_uint(pk1.w);
            int sp0 = (g0 == 1) ? (int)(b0 & 7u) : (int)(b0 >> 3);
            int sp1 = (g1 == 1) ? (int)(b1 & 7u) : (int)(b1 >> 3);
            float s01 = (float)(g0 * g1);

            float n0 = v0x * v0x + v0y * v0y + v0z * v0z;
            float n1 = v1x * v1x + v1y * v1y + v1z * v1z;
            float r0 = rsqrtf(n0), r1 = rsqrtf(n1);
            float d0 = n0 * r0,    d1 = n1 * r1;
            float dot = v0x * v1x + v0y * v1y + v0z * v1z;
            float ca = 0.95f * dot * r0 * r1 * s01;
            float sa = sqrtf(fmaxf(0.0f, 1.0f - ca * ca));

            float fc0 = (d0 < RCA) ? (0.5f * __cosf((PI_F / RCA) * d0) + 0.5f) : 0.0f;
            float fc1 = (d1 < RCA) ? (0.5f * __cosf((PI_F / RCA) * d1) + 0.5f) : 0.0f;
            float pref = 2.0f * fc0 * fc1;
            float davg = 0.5f * (d0 + d1);

            int aa = min(sp0, sp1), bb = max(sp0, sp1);
            int triu = aa * S - (aa * (aa - 1)) / 2 + (bb - aa);

            int sb = lane * 13;
#pragma unroll
            for (int ai = 0; ai < NA; ++ai) {
                float dd = davg - (RAMIN + ai * ASTEP);
                scr[sb + ai] = pref * __expf(-ETA_A * dd * dd);
            }
#pragma unroll
            for (int z = 0; z < NZ; ++z)
                scr[sb + 8 + z] = __powf(0.5f * (1.0f + ca * CZV[z] + sa * SZV[z]), ZETA);
            scr[sb + 12] = __int_as_float(triu);
        }
        // phase 2: 2 triples per iteration, all 64 lanes.
        // half 0 (lanes 0-31) takes even triple, half 1 odd. Cross-half
        // exchange (tr,val); on collision half 0 merges both, half 1 skips.
        // Banks: half0 hits (s+tr_e)%32, half1 (s+tr_o)%32 -> exactly 2
        // lanes/bank (free); addresses distinct when tr_e != tr_o.
        {
            int m = min(64, end - base);
            const int half = lane >> 5;
            const int s    = lane & 31;
            const int q    = s >> 2, z = s & 3;
            for (int u = 0; u < m; u += 2) {
                int t2 = u + half;
                bool has = (t2 < m);
                float pfv = 0.f, f1v = 0.f;
                int tr = 0;
                if (has) {
                    pfv = scr[t2 * 13 + q];
                    f1v = scr[t2 * 13 + 8 + z];
                    tr  = __float_as_int(scr[t2 * 13 + 12]);
                }
                float val = pfv * f1v;
                int   tr_o  = __shfl_xor(tr, 32);
                float val_o = __shfl_xor(val, 32);
                bool same = (tr_o == tr) && (u + 1 < m);
                float add = val + ((half == 0 && same) ? val_o : 0.f);
                bool doit = (half == 0) || (has && !same);
                if (doit) A[s * 33 + tr] += add;
            }
        }
    }

    // ---- write angular row (sub-minor output layout: col = triu*32 + s) ----
#pragma unroll
    for (int q = 0; q < ANG_W / 64; ++q) {
        int kk = q * 64 + lane;
        o[RAD_W + kk] = A[(kk & 31) * 33 + (kk >> 5)];
    }
}

// ---------------- radial fallback A: CSR (hist/scan/scatter) ----------------

__global__ __launch_bounds__(256)
void zero_cnt_kernel(int* __restrict__ cnt) {
    int i = blockIdx.x * blockDim.x + threadIdx.x;
    if (i < NATOMS) cnt[i] = 0;
}

__global__ __launch_bounds__(256)
void hist_kernel(const int* __restrict__ pair_indices, int* __restrict__ cnt) {
    int p = blockIdx.x * blockDim.x + threadIdx.x;
    if (p >= P) return;
    atomicAdd(&cnt[pair_indices[p]], 1);
    atomicAdd(&cnt[pair_indices[P + p]], 1);
}

__global__ __launch_bounds__(256)
void scan1_kernel(const int* __restrict__ cnt, int* __restrict__ off,
                  int* __restrict__ chunk) {
    __shared__ int s[256];
    int t = threadIdx.x;
    int base = blockIdx.x * CHUNK + t * 4;
    int v[4]; int sum = 0;
#pragma unroll
    for (int q = 0; q < 4; ++q) {
        int idx = base + q;
        v[q] = (idx < NATOMS) ? cnt[idx] : 0;
        sum += v[q];
    }
    s[t] = sum;
    __syncthreads();
    for (int d2 = 1; d2 < 256; d2 <<= 1) {
        int x = (t >= d2) ? s[t - d2] : 0;
        __syncthreads();
        s[t] += x;
        __syncthreads();
    }
    int excl = s[t] - sum;
#pragma unroll
    for (int q = 0; q < 4; ++q) {
        int idx = base + q;
        if (idx < NATOMS) off[idx] = excl;
        excl += v[q];
    }
    if (t == 255) chunk[blockIdx.x] = s[255];
}

__global__ __launch_bounds__(64)
void scan2_kernel(const int* __restrict__ chunk, int* __restrict__ chunk_excl) {
    if (threadIdx.x == 0) {
        int run = 0;
        for (int b = 0; b < NCHUNK; ++b) { chunk_excl[b] = run; run += chunk[b]; }
        chunk_excl[NCHUNK] = run;
    }
}

__global__ __launch_bounds__(256)
void scan3_kernel(int* __restrict__ off, int* __restrict__ cur,
                  const int* __restrict__ chunk_excl) {
    int i = blockIdx.x * blockDim.x + threadIdx.x;
    if (i >= NATOMS) return;
    int o = off[i] + chunk_excl[i / CHUNK];
    off[i] = o;
    cur[i] = o;
    if (i == 0) off[NATOMS] = chunk_excl[NCHUNK];
}

__global__ __launch_bounds__(256)
void scatter_csr_kernel(const int* __restrict__ pair_indices,
                        const int* __restrict__ atom_index,
                        const float* __restrict__ d_ij,
                        int* __restrict__ cur,
                        unsigned* __restrict__ ent) {
    int p = blockIdx.x * blockDim.x + threadIdx.x;
    if (p >= P) return;
    int i = pair_indices[p];
    int j = pair_indices[P + p];
    int si = atom_index[i];
    int sj = atom_index[j];
    unsigned base = ((unsigned)__float2uint_rn(d_ij[p] * DPACK)) << 16;
    int pos0 = atomicAdd(&cur[i], 1);
    ent[pos0] = base | (unsigned)sj;
    int pos1 = atomicAdd(&cur[j], 1);
    ent[pos1] = base | (unsigned)si;
}

__global__ __launch_bounds__(64)
void radial_rows_csr_kernel(const int* __restrict__ off,
                            const unsigned* __restrict__ ent,
                            float* __restrict__ out) {
    __shared__ float row[RAD_W];
    int a = blockIdx.x, lane = threadIdx.x;
    row[lane] = 0.0f;
    if (lane < RAD_W - 64) row[64 + lane] = 0.0f;
    __syncthreads();

    int start = off[a], end = off[a + 1];
    int k = lane & 15, q = lane >> 4;
    for (int e0 = start; e0 < end; e0 += 4) {
        int e = e0 + q;
        if (e < end) {
            unsigned u = ent[e];
            float d  = (float)(u >> 16) * DUNPACK;
            int   sp = (int)(u & 7u);
            float fc = (d < RC) ? (0.5f * __cosf((PI_F / RC) * d) + 0.5f) : 0.0f;
            float dd = d - (RMIN + k * RSTEP);
            atomicAdd(&row[sp * NRBF + k], 0.25f * __expf(-ETA_R * dd * dd) * fc);
        }
    }
    __syncthreads();
    float* o = out + (size_t)a * AEV;
    o[lane] = row[lane];
    if (lane < RAD_W - 64) o[64 + lane] = row[64 + lane];
}

// ---------------- radial fallback B: direct atomics ----------------

__global__ __launch_bounds__(256)
void radial_atomic_kernel(const int* __restrict__ atom_index,
                          const int* __restrict__ pair_indices,
                          const float* __restrict__ d_ij,
                          float* __restrict__ out) {
    int p = blockIdx.x * blockDim.x + threadIdx.x;
    if (p >= P) return;
    float d = d_ij[p];
    int i = pair_indices[p];
    int j = pair_indices[P + p];
    int si = atom_index[i];
    int sj = atom_index[j];
    float fc = (d < RC) ? (0.5f * __cosf((PI_F / RC) * d) + 0.5f) : 0.0f;
    float t[NRBF];
#pragma unroll
    for (int k = 0; k < NRBF; ++k) {
        float dd = d - (RMIN + k * RSTEP);
        t[k] = 0.25f * __expf(-ETA_R * dd * dd) * fc;
    }
    float* o0 = out + (size_t)i * AEV + sj * NRBF;
    float* o1 = out + (size_t)j * AEV + si * NRBF;
#pragma unroll
    for (int k = 0; k < NRBF; ++k) atomicAdd(o0 + k, t[k]);
#pragma unroll
    for (int k = 0; k < NRBF; ++k) atomicAdd(o1 + k, t[k]);
}

__global__ __launch_bounds__(256)
void zero_radial_kernel(float* __restrict__ out) {
    long long i = (long long)blockIdx.x * blockDim.x + threadIdx.x;
    long long n = (long long)NATOMS * RAD_W;
    if (i >= n) return;
    long long a = i / RAD_W, k = i % RAD_W;
    out[a * AEV + k] = 0.0f;
}

// ---------------- old angular (binary search) for fallback paths ----------------

__device__ __forceinline__ int lower_bound(const int* __restrict__ arr, int n, int key) {
    int lo = 0, hi = n;
    while (lo < hi) {
        int mid = (lo + hi) >> 1;
        if (arr[mid] < key) lo = mid + 1; else hi = mid;
    }
    return lo;
}

__global__ __launch_bounds__(64)
void angular_rows_kernel(const int* __restrict__ atom_index,
                         const int* __restrict__ pair_indices,
                         const float* __restrict__ r_ij,
                         const int* __restrict__ central,
                         const int* __restrict__ pidx12,
                         const int* __restrict__ sign12,
                         float* __restrict__ out, int T) {
    __shared__ float row[ANG_W];
    int a = blockIdx.x, lane = threadIdx.x;

#pragma unroll
    for (int q = 0; q < ANG_W / 64; ++q) row[q * 64 + lane] = 0.0f;
    __syncthreads();

    int start = lower_bound(central, T, a);
    int end   = lower_bound(central, T, a + 1);

    const float CZV[NZ] = { 0.92387953f,  0.38268343f, -0.38268343f, -0.92387953f };
    const float SZV[NZ] = { 0.38268343f,  0.92387953f,  0.92387953f,  0.38268343f };

    for (int t = start + lane; t < end; t += 64) {
        int p0 = pidx12[t];
        int p1 = pidx12[T + t];
        int g0 = sign12[t];
        int g1 = sign12[T + t];
        float s0f = (float)g0, s1f = (float)g1;

        float v0x = r_ij[3 * p0    ] * s0f;
        float v0y = r_ij[3 * p0 + 1] * s0f;
        float v0z = r_ij[3 * p0 + 2] * s0f;
        float v1x = r_ij[3 * p1    ] * s1f;
        float v1y = r_ij[3 * p1 + 1] * s1f;
        float v1z = r_ij[3 * p1 + 2] * s1f;

        float n0 = v0x * v0x + v0y * v0y + v0z * v0z;
        float n1 = v1x * v1x + v1y * v1y + v1z * v1z;
        float r0 = rsqrtf(n0), r1 = rsqrtf(n1);
        float d0 = n0 * r0,    d1 = n1 * r1;
        float dot = v0x * v1x + v0y * v1y + v0z * v1z;
        float ca = 0.95f * dot * r0 * r1;
        float sa = sqrtf(fmaxf(0.0f, 1.0f - ca * ca));

        float fc0 = (d0 < RCA) ? (0.5f * __cosf((PI_F / RCA) * d0) + 0.5f) : 0.0f;
        float fc1 = (d1 < RCA) ? (0.5f * __cosf((PI_F / RCA) * d1) + 0.5f) : 0.0f;
        float pref = 2.0f * fc0 * fc1;
        float davg = 0.5f * (d0 + d1);

        float f1[NZ];
#pragma unroll
        for (int z = 0; z < NZ; ++z)
            f1[z] = __powf(0.5f * (1.0f + ca * CZV[z] + sa * SZV[z]), ZETA);

        float pf[NA];
#pragma unroll
        for (int ai = 0; ai < NA; ++ai) {
            float dd = davg - (RAMIN + ai * ASTEP);
            pf[ai] = pref * __expf(-ETA_A * dd * dd);
        }

        int i0 = pair_indices[p0], j0 = pair_indices[P + p0];
        int i1 = pair_indices[p1], j1 = pair_indices[P + p1];
        int sp0 = atom_index[(g0 == 1) ? j0 : i0];
        int sp1 = atom_index[(g1 == 1) ? j1 : i1];
        int aa = min(sp0, sp1), bb = max(sp0, sp1);
        int triu = aa * S - (aa * (aa - 1)) / 2 + (bb - aa);

#pragma unroll
        for (int s = 0; s < SUB; ++s)
            atomicAdd(&row[s * NPAIRS + triu], pf[s >> 2] * f1[s & 3]);
    }
    __syncthreads();

    float* o = out + (size_t)a * AEV + RAD_W;
#pragma unroll
    for (int q = 0; q < ANG_W / 64; ++q) {
        int kk = q * 64 + lane;
        int triu = kk >> 5, s = kk & 31;
        o[kk] = row[s * NPAIRS + triu];
    }
}

// ---------------- launch ----------------

extern "C" void kernel_launch(void* const* d_in, const int* in_sizes, int n_in,
                              void* d_out, int out_size, void* d_ws, size_t ws_size,
                              hipStream_t stream) {
    const int*   atom_index   = (const int*)d_in[0];
    const int*   pair_indices = (const int*)d_in[1];
    const float* d_ij         = (const float*)d_in[2];
    const float* r_ij         = (const float*)d_in[3];
    const int*   central      = (const int*)d_in[4];
    const int*   pidx12       = (const int*)d_in[5];
    const int*   sign12       = (const int*)d_in[6];
    float*       out          = (float*)d_out;
    const int    T            = in_sizes[4];

    // preferred: packed pairs + fixed-capacity bins + triple offsets + v7 fused
    float4*   packed = (float4*)d_ws;
    unsigned* binsP  = (unsigned*)(packed + PA);
    int*      bcntP  = (int*)(binsP + (size_t)NATOMS * CAP);
    int*      toffP  = bcntP + NATOMS;
    size_t need_packed = (size_t)PA * 16 + (size_t)NATOMS * CAP * 4
                       + (size_t)NATOMS * 4 + (size_t)(NATOMS + 1) * 4;

    // fallback: CSR
    unsigned* ent = (unsigned*)d_ws;
    int* ints = (int*)(ent + 2 * (size_t)P);
    int* cnt        = ints;
    int* off        = cnt + NATOMS;
    int* cur        = off + NATOMS + 1;
    int* chunk      = cur + NATOMS;
    int* chunk_excl = chunk + NCHUNK;
    size_t need_csr = (char*)(chunk_excl + NCHUNK + 1) - (char*)d_ws;

    if (ws_size >= need_packed) {
        hipMemsetAsync(bcntP, 0, (size_t)NATOMS * 4, stream);
        if (T <= 0) {
            hipMemsetAsync(toffP, 0, (size_t)(NATOMS + 1) * 4, stream);
        }
        int work = (PQ > T) ? PQ : T;
        scatter_binned_kernel<<<(work + 255) / 256, 256, 0, stream>>>(
            pair_indices, atom_index, d_ij, r_ij, bcntP, binsP, packed,
            central, (T > 0) ? toffP : nullptr, T);
        fused_rows2_kernel<<<NATOMS / APB, 256, 0, stream>>>(
            bcntP, binsP, pidx12, sign12, toffP, packed, out, T);
    } else if (ws_size >= need_csr) {
        zero_cnt_kernel<<<(NATOMS + 255) / 256, 256, 0, stream>>>(cnt);
        hist_kernel<<<(P + 255) / 256, 256, 0, stream>>>(pair_indices, cnt);
        scan1_kernel<<<NCHUNK, 256, 0, stream>>>(cnt, off, chunk);
        scan2_kernel<<<1, 64, 0, stream>>>(chunk, chunk_excl);
        scan3_kernel<<<(NATOMS + 255) / 256, 256, 0, stream>>>(off, cur, chunk_excl);
        scatter_csr_kernel<<<(P + 255) / 256, 256, 0, stream>>>(pair_indices, atom_index,
                                                                d_ij, cur, ent);
        radial_rows_csr_kernel<<<NATOMS, 64, 0, stream>>>(off, ent, out);
        angular_rows_kernel<<<NATOMS, 64, 0, stream>>>(atom_index, pair_indices, r_ij,
                                                       central, pidx12, sign12, out, T);
    } else {
        zero_radial_kernel<<<((long long)NATOMS * RAD_W + 255) / 256, 256, 0, stream>>>(out);
        radial_atomic_kernel<<<(P + 255) / 256, 256, 0, stream>>>(atom_index, pair_indices,
                                                                  d_ij, out);
        angular_rows_kernel<<<NATOMS, 64, 0, stream>>>(atom_index, pair_indices, r_ij,
                                                       central, pidx12, sign12, out, T);
    }
}

// Round 8
// 477.819 us; speedup vs baseline: 1.1648x; 1.1648x over previous
//
#include <hip/hip_runtime.h>

// ANI AEV (radial + angular), scatter-free output writes.
// v8: scatter_binned reverted to 1 pair/thread full grid (R7's 4-pair ILP
// regressed: kernel is scattered-line-throughput bound, wants max waves).
// Keeps v7 fused phase-2 (2 triples/iter, all 64 lanes, shfl_xor merge) and
// v6 LDS aliasing (31744 B/block) + tri_off/pack fusion.

constexpr int   NATOMS = 50000;
constexpr int   P      = 1000000;
constexpr int   PA     = 200000;
constexpr int   S      = 7;
constexpr int   NRBF   = 16;
constexpr float RC     = 0.51f;
constexpr float RMIN   = 0.08f;
constexpr float RCA    = 0.35f;
constexpr float RAMIN  = 0.08f;
constexpr int   NA     = 8;
constexpr int   NZ     = 4;
constexpr float ETA_R  = 1970.0f;
constexpr float ETA_A  = 1250.0f;
constexpr float ZETA   = 14.1f;
constexpr int   NPAIRS = 28;
constexpr int   SUB    = 32;
constexpr int   RAD_W  = S * NRBF;      // 112
constexpr int   ANG_W  = NPAIRS * SUB;  // 896
constexpr int   AEV    = RAD_W + ANG_W; // 1008

constexpr float RSTEP  = (RC  - RMIN ) / NRBF;
constexpr float ASTEP  = (RCA - RAMIN) / NA;
constexpr float PI_F   = 3.14159265358979f;

constexpr int   CAP    = 96;                 // per-atom bin capacity (mean 40)
constexpr float DPACK   = 65535.0f / 0.52f;  // d in [0,0.52) -> 16-bit fixed
constexpr float DUNPACK = 0.52f / 65535.0f;

constexpr int   APB    = 4;                  // atoms (waves) per block

// per-wave LDS layout (floats): A[32*33]=1056 | scr[64*13]=832 | rsc[96]
// arad[4*112]=448 is ALIASED onto scr[0..447] (radial phase only).
constexpr int   A_WORDS  = 32 * 33;
constexpr int   SC_WORDS = 64 * 13;
constexpr int   RS_WORDS = CAP;
constexpr int   WLDS     = A_WORDS + SC_WORDS + RS_WORDS;  // 1984 -> 31744 B/blk

constexpr int   CHUNK  = 1024;
constexpr int   NCHUNK = (NATOMS + CHUNK - 1) / CHUNK;

// ------- radial binning + angular pair packing + triple offsets (fused) -------
// 1 pair/thread, full grid: scattered-line stores want maximum wave count.

__global__ __launch_bounds__(256)
void scatter_binned_kernel(const int* __restrict__ pair_indices,
                           const int* __restrict__ atom_index,
                           const float* __restrict__ d_ij,
                           const float* __restrict__ r_ij,
                           int* __restrict__ cnt,
                           unsigned* __restrict__ bins,
                           float4* __restrict__ packed,
                           const int* __restrict__ central,
                           int* __restrict__ toff, int T) {
    int p = blockIdx.x * blockDim.x + threadIdx.x;

    // --- tri_off part (threads p < T) ---
    if (toff != nullptr && p < T) {
        int c = central[p];
        if (p == 0) {
            for (int a = 0; a <= c; ++a) toff[a] = 0;
        } else {
            int cp = central[p - 1];
            for (int a = cp + 1; a <= c; ++a) toff[a] = p;
        }
        if (p == T - 1) {
            for (int a = c + 1; a <= NATOMS; ++a) toff[a] = T;
        }
    }

    if (p >= P) return;
    int i = pair_indices[p];
    int j = pair_indices[P + p];
    int si = atom_index[i];
    int sj = atom_index[j];
    if (packed != nullptr && p < PA) {
        unsigned bits = ((unsigned)si << 3) | (unsigned)sj;
        float4 v;
        v.x = r_ij[3 * p    ];
        v.y = r_ij[3 * p + 1];
        v.z = r_ij[3 * p + 2];
        v.w = __uint_as_float(bits);
        packed[p] = v;
    }
    unsigned dfix = (unsigned)__float2uint_rn(d_ij[p] * DPACK);
    unsigned base = dfix << 16;
    int pos0 = atomicAdd(&cnt[i], 1);
    if (pos0 < CAP) bins[(size_t)i * CAP + pos0] = base | (unsigned)sj;
    int pos1 = atomicAdd(&cnt[j], 1);
    if (pos1 < CAP) bins[(size_t)j * CAP + pos1] = base | (unsigned)si;
}

// ---------------- v8 fused per-atom row build: NO atomics ----------------

__global__ __launch_bounds__(256)
void fused_rows2_kernel(const int* __restrict__ cnt,
                        const unsigned* __restrict__ bins,
                        const int* __restrict__ pidx12,
                        const int* __restrict__ sign12,
                        const int* __restrict__ toff,
                        const float4* __restrict__ packed,
                        float* __restrict__ out, int T) {
    __shared__ float lds[APB * WLDS];

    const int w    = threadIdx.x >> 6;
    const int lane = threadIdx.x & 63;
    const int a    = blockIdx.x * APB + w;   // grid sized exactly NATOMS/APB

    float* A    = lds + w * WLDS;            // [32][33] lane-private rows
    float* scr  = A + A_WORDS;               // [64][13] per-triple scalars
    float* rsc  = scr + SC_WORDS;            // [CAP] radial entries
    float* arad = scr;                       // [4][112] ALIAS (radial phase only)

    // zero angular accumulator (264 float4)
    float4* A4 = (float4*)A;
#pragma unroll
    for (int q = 0; q < 5; ++q) {
        int idx = q * 64 + lane;
        if (idx < A_WORDS / 4) A4[idx] = make_float4(0.f, 0.f, 0.f, 0.f);
    }
    // zero radial accumulator (448 = 7*64) -- lives in scr for now
#pragma unroll
    for (int q = 0; q < 7; ++q) arad[q * 64 + lane] = 0.0f;

    // triple range; issue first-chunk gathers early (hidden under radial)
    const int start = toff[a];
    const int end   = toff[a + 1];
    const int t0    = start + lane;
    int p0 = 0, p1 = 0, g0 = 1, g1 = 1;
    float4 pk0 = make_float4(1.f, 0.f, 0.f, 0.f);
    float4 pk1 = make_float4(1.f, 0.f, 0.f, 0.f);
    if (t0 < end) {
        p0 = pidx12[t0];
        p1 = pidx12[T + t0];
        g0 = sign12[t0];
        g1 = sign12[T + t0];
        pk0 = packed[p0];
        pk1 = packed[p1];
    }

    // ---- radial phase: 4 entries per pass, q-replicated LDS scatter ----
    const int n = min(cnt[a], CAP);
    const unsigned* b = bins + (size_t)a * CAP;
    if (lane < n)      rsc[lane]      = __uint_as_float(b[lane]);
    if (64 + lane < n) rsc[64 + lane] = __uint_as_float(b[64 + lane]);

    const int k  = lane & 15, qg = lane >> 4;
    const float muk = RMIN + k * RSTEP;
    float* arq = arad + qg * RAD_W;          // this q-group's region
    for (int e0 = 0; e0 < n; e0 += 4) {
        int e = e0 + qg;
        if (e < n) {
            unsigned u = __float_as_uint(rsc[e]);
            float d  = (float)(u >> 16) * DUNPACK;
            int   sp = (int)(u & 7u);
            float fc = (d < RC) ? (0.5f * __cosf((PI_F / RC) * d) + 0.5f) : 0.0f;
            float dd = d - muk;
            float rbf = 0.25f * __expf(-ETA_R * dd * dd) * fc;
            arq[sp * NRBF + k] += rbf;       // distinct (qg, sp, k) addresses
        }
    }
    float* o = out + (size_t)a * AEV;
    {
        float v = arad[lane] + arad[RAD_W + lane] + arad[2 * RAD_W + lane]
                + arad[3 * RAD_W + lane];
        o[lane] = v;
        if (lane < RAD_W - 64) {
            int e2 = 64 + lane;
            float v2 = arad[e2] + arad[RAD_W + e2] + arad[2 * RAD_W + e2]
                     + arad[3 * RAD_W + e2];
            o[e2] = v2;
        }
    }
    // radial done; scr free for angular scratch (wave-private, sequential)

    // ---- angular: phase-1 per-triple scalars -> phase-2 paired accumulate ----
    const float CZV[NZ] = { 0.92387953f,  0.38268343f, -0.38268343f, -0.92387953f };
    const float SZV[NZ] = { 0.38268343f,  0.92387953f,  0.92387953f,  0.38268343f };

    for (int base = start; base < end; base += 64) {
        int t = base + lane;
        bool act = t < end;
        if (base != start && act) {
            p0 = pidx12[t];
            p1 = pidx12[T + t];
            g0 = sign12[t];
            g1 = sign12[T + t];
            pk0 = packed[p0];
            pk1 = packed[p1];
        }
        if (act) {
            float v0x = pk0.x, v0y = pk0.y, v0z = pk0.z;
            float v1x = pk1.x, v1y = pk1.y, v1z = pk1.z;
            unsigned b0 = __float_as_uint(pk0.w);
            unsigned b1 = __float_as_uint(pk1.w);
            int sp0 = (g0 == 1) ? (int)(b0 & 7u) : (int)(b0 >> 3);
            int sp1 = (g1 == 1) ? (int)(b1 & 7u) : (int)(b1 >> 3);
            float s01 = (float)(g0 * g1);

            float n0 = v0x * v0x + v0y * v0y + v0z * v0z;
            float n1 = v1x * v1x + v1y * v1y + v1z * v1z;
            float r0 = rsqrtf(n0), r1 = rsqrtf(n1);
            float d0 = n0 * r0,    d1 = n1 * r1;
            float dot = v0x * v1x + v0y * v1y + v0z * v1z;
            float ca = 0.95f * dot * r0 * r1 * s01;
            float sa = sqrtf(fmaxf(0.0f, 1.0f - ca * ca));

            float fc0 = (d0 < RCA) ? (0.5f * __cosf((PI_F / RCA) * d0) + 0.5f) : 0.0f;
            float fc1 = (d1 < RCA) ? (0.5f * __cosf((PI_F / RCA) * d1) + 0.5f) : 0.0f;
            float pref = 2.0f * fc0 * fc1;
            float davg = 0.5f * (d0 + d1);

            int aa = min(sp0, sp1), bb = max(sp0, sp1);
            int triu = aa * S - (aa * (aa - 1)) / 2 + (bb - aa);

            int sb = lane * 13;
#pragma unroll
            for (int ai = 0; ai < NA; ++ai) {
                float dd = davg - (RAMIN + ai * ASTEP);
                scr[sb + ai] = pref * __expf(-ETA_A * dd * dd);
            }
#pragma unroll
            for (int z = 0; z < NZ; ++z)
                scr[sb + 8 + z] = __powf(0.5f * (1.0f + ca * CZV[z] + sa * SZV[z]), ZETA);
            scr[sb + 12] = __int_as_float(triu);
        }
        // phase 2: 2 triples per iteration, all 64 lanes.
        // half 0 (lanes 0-31) takes even triple, half 1 odd. Cross-half
        // exchange (tr,val); on collision half 0 merges both, half 1 skips.
        {
            int m = min(64, end - base);
            const int half = lane >> 5;
            const int s    = lane & 31;
            const int q    = s >> 2, z = s & 3;
            for (int u = 0; u < m; u += 2) {
                int t2 = u + half;
                bool has = (t2 < m);
                float pfv = 0.f, f1v = 0.f;
                int tr = 0;
                if (has) {
                    pfv = scr[t2 * 13 + q];
                    f1v = scr[t2 * 13 + 8 + z];
                    tr  = __float_as_int(scr[t2 * 13 + 12]);
                }
                float val = pfv * f1v;
                int   tr_o  = __shfl_xor(tr, 32);
                float val_o = __shfl_xor(val, 32);
                bool same = (tr_o == tr) && (u + 1 < m);
                float add = val + ((half == 0 && same) ? val_o : 0.f);
                bool doit = (half == 0) || (has && !same);
                if (doit) A[s * 33 + tr] += add;
            }
        }
    }

    // ---- write angular row (sub-minor output layout: col = triu*32 + s) ----
#pragma unroll
    for (int q = 0; q < ANG_W / 64; ++q) {
        int kk = q * 64 + lane;
        o[RAD_W + kk] = A[(kk & 31) * 33 + (kk >> 5)];
    }
}

// ---------------- radial fallback A: CSR (hist/scan/scatter) ----------------

__global__ __launch_bounds__(256)
void zero_cnt_kernel(int* __restrict__ cnt) {
    int i = blockIdx.x * blockDim.x + threadIdx.x;
    if (i < NATOMS) cnt[i] = 0;
}

__global__ __launch_bounds__(256)
void hist_kernel(const int* __restrict__ pair_indices, int* __restrict__ cnt) {
    int p = blockIdx.x * blockDim.x + threadIdx.x;
    if (p >= P) return;
    atomicAdd(&cnt[pair_indices[p]], 1);
    atomicAdd(&cnt[pair_indices[P + p]], 1);
}

__global__ __launch_bounds__(256)
void scan1_kernel(const int* __restrict__ cnt, int* __restrict__ off,
                  int* __restrict__ chunk) {
    __shared__ int s[256];
    int t = threadIdx.x;
    int base = blockIdx.x * CHUNK + t * 4;
    int v[4]; int sum = 0;
#pragma unroll
    for (int q = 0; q < 4; ++q) {
        int idx = base + q;
        v[q] = (idx < NATOMS) ? cnt[idx] : 0;
        sum += v[q];
    }
    s[t] = sum;
    __syncthreads();
    for (int d2 = 1; d2 < 256; d2 <<= 1) {
        int x = (t >= d2) ? s[t - d2] : 0;
        __syncthreads();
        s[t] += x;
        __syncthreads();
    }
    int excl = s[t] - sum;
#pragma unroll
    for (int q = 0; q < 4; ++q) {
        int idx = base + q;
        if (idx < NATOMS) off[idx] = excl;
        excl += v[q];
    }
    if (t == 255) chunk[blockIdx.x] = s[255];
}

__global__ __launch_bounds__(64)
void scan2_kernel(const int* __restrict__ chunk, int* __restrict__ chunk_excl) {
    if (threadIdx.x == 0) {
        int run = 0;
        for (int b = 0; b < NCHUNK; ++b) { chunk_excl[b] = run; run += chunk[b]; }
        chunk_excl[NCHUNK] = run;
    }
}

__global__ __launch_bounds__(256)
void scan3_kernel(int* __restrict__ off, int* __restrict__ cur,
                  const int* __restrict__ chunk_excl) {
    int i = blockIdx.x * blockDim.x + threadIdx.x;
    if (i >= NATOMS) return;
    int o = off[i] + chunk_excl[i / CHUNK];
    off[i] = o;
    cur[i] = o;
    if (i == 0) off[NATOMS] = chunk_excl[NCHUNK];
}

__global__ __launch_bounds__(256)
void scatter_csr_kernel(const int* __restrict__ pair_indices,
                        const int* __restrict__ atom_index,
                        const float* __restrict__ d_ij,
                        int* __restrict__ cur,
                        unsigned* __restrict__ ent) {
    int p = blockIdx.x * blockDim.x + threadIdx.x;
    if (p >= P) return;
    int i = pair_indices[p];
    int j = pair_indices[P + p];
    int si = atom_index[i];
    int sj = atom_index[j];
    unsigned base = ((unsigned)__float2uint_rn(d_ij[p] * DPACK)) << 16;
    int pos0 = atomicAdd(&cur[i], 1);
    ent[pos0] = base | (unsigned)sj;
    int pos1 = atomicAdd(&cur[j], 1);
    ent[pos1] = base | (unsigned)si;
}

__global__ __launch_bounds__(64)
void radial_rows_csr_kernel(const int* __restrict__ off,
                            const unsigned* __restrict__ ent,
                            float* __restrict__ out) {
    __shared__ float row[RAD_W];
    int a = blockIdx.x, lane = threadIdx.x;
    row[lane] = 0.0f;
    if (lane < RAD_W - 64) row[64 + lane] = 0.0f;
    __syncthreads();

    int start = off[a], end = off[a + 1];
    int k = lane & 15, q = lane >> 4;
    for (int e0 = start; e0 < end; e0 += 4) {
        int e = e0 + q;
        if (e < end) {
            unsigned u = ent[e];
            float d  = (float)(u >> 16) * DUNPACK;
            int   sp = (int)(u & 7u);
            float fc = (d < RC) ? (0.5f * __cosf((PI_F / RC) * d) + 0.5f) : 0.0f;
            float dd = d - (RMIN + k * RSTEP);
            atomicAdd(&row[sp * NRBF + k], 0.25f * __expf(-ETA_R * dd * dd) * fc);
        }
    }
    __syncthreads();
    float* o = out + (size_t)a * AEV;
    o[lane] = row[lane];
    if (lane < RAD_W - 64) o[64 + lane] = row[64 + lane];
}

// ---------------- radial fallback B: direct atomics ----------------

__global__ __launch_bounds__(256)
void radial_atomic_kernel(const int* __restrict__ atom_index,
                          const int* __restrict__ pair_indices,
                          const float* __restrict__ d_ij,
                          float* __restrict__ out) {
    int p = blockIdx.x * blockDim.x + threadIdx.x;
    if (p >= P) return;
    float d = d_ij[p];
    int i = pair_indices[p];
    int j = pair_indices[P + p];
    int si = atom_index[i];
    int sj = atom_index[j];
    float fc = (d < RC) ? (0.5f * __cosf((PI_F / RC) * d) + 0.5f) : 0.0f;
    float t[NRBF];
#pragma unroll
    for (int k = 0; k < NRBF; ++k) {
        float dd = d - (RMIN + k * RSTEP);
        t[k] = 0.25f * __expf(-ETA_R * dd * dd) * fc;
    }
    float* o0 = out + (size_t)i * AEV + sj * NRBF;
    float* o1 = out + (size_t)j * AEV + si * NRBF;
#pragma unroll
    for (int k = 0; k < NRBF; ++k) atomicAdd(o0 + k, t[k]);
#pragma unroll
    for (int k = 0; k < NRBF; ++k) atomicAdd(o1 + k, t[k]);
}

__global__ __launch_bounds__(256)
void zero_radial_kernel(float* __restrict__ out) {
    long long i = (long long)blockIdx.x * blockDim.x + threadIdx.x;
    long long n = (long long)NATOMS * RAD_W;
    if (i >= n) return;
    long long a = i / RAD_W, k = i % RAD_W;
    out[a * AEV + k] = 0.0f;
}

// ---------------- old angular (binary search) for fallback paths ----------------

__device__ __forceinline__ int lower_bound(const int* __restrict__ arr, int n, int key) {
    int lo = 0, hi = n;
    while (lo < hi) {
        int mid = (lo + hi) >> 1;
        if (arr[mid] < key) lo = mid + 1; else hi = mid;
    }
    return lo;
}

__global__ __launch_bounds__(64)
void angular_rows_kernel(const int* __restrict__ atom_index,
                         const int* __restrict__ pair_indices,
                         const float* __restrict__ r_ij,
                         const int* __restrict__ central,
                         const int* __restrict__ pidx12,
                         const int* __restrict__ sign12,
                         float* __restrict__ out, int T) {
    __shared__ float row[ANG_W];
    int a = blockIdx.x, lane = threadIdx.x;

#pragma unroll
    for (int q = 0; q < ANG_W / 64; ++q) row[q * 64 + lane] = 0.0f;
    __syncthreads();

    int start = lower_bound(central, T, a);
    int end   = lower_bound(central, T, a + 1);

    const float CZV[NZ] = { 0.92387953f,  0.38268343f, -0.38268343f, -0.92387953f };
    const float SZV[NZ] = { 0.38268343f,  0.92387953f,  0.92387953f,  0.38268343f };

    for (int t = start + lane; t < end; t += 64) {
        int p0 = pidx12[t];
        int p1 = pidx12[T + t];
        int g0 = sign12[t];
        int g1 = sign12[T + t];
        float s0f = (float)g0, s1f = (float)g1;

        float v0x = r_ij[3 * p0    ] * s0f;
        float v0y = r_ij[3 * p0 + 1] * s0f;
        float v0z = r_ij[3 * p0 + 2] * s0f;
        float v1x = r_ij[3 * p1    ] * s1f;
        float v1y = r_ij[3 * p1 + 1] * s1f;
        float v1z = r_ij[3 * p1 + 2] * s1f;

        float n0 = v0x * v0x + v0y * v0y + v0z * v0z;
        float n1 = v1x * v1x + v1y * v1y + v1z * v1z;
        float r0 = rsqrtf(n0), r1 = rsqrtf(n1);
        float d0 = n0 * r0,    d1 = n1 * r1;
        float dot = v0x * v1x + v0y * v1y + v0z * v1z;
        float ca = 0.95f * dot * r0 * r1;
        float sa = sqrtf(fmaxf(0.0f, 1.0f - ca * ca));

        float fc0 = (d0 < RCA) ? (0.5f * __cosf((PI_F / RCA) * d0) + 0.5f) : 0.0f;
        float fc1 = (d1 < RCA) ? (0.5f * __cosf((PI_F / RCA) * d1) + 0.5f) : 0.0f;
        float pref = 2.0f * fc0 * fc1;
        float davg = 0.5f * (d0 + d1);

        float f1[NZ];
#pragma unroll
        for (int z = 0; z < NZ; ++z)
            f1[z] = __powf(0.5f * (1.0f + ca * CZV[z] + sa * SZV[z]), ZETA);

        float pf[NA];
#pragma unroll
        for (int ai = 0; ai < NA; ++ai) {
            float dd = davg - (RAMIN + ai * ASTEP);
            pf[ai] = pref * __expf(-ETA_A * dd * dd);
        }

        int i0 = pair_indices[p0], j0 = pair_indices[P + p0];
        int i1 = pair_indices[p1], j1 = pair_indices[P + p1];
        int sp0 = atom_index[(g0 == 1) ? j0 : i0];
        int sp1 = atom_index[(g1 == 1) ? j1 : i1];
        int aa = min(sp0, sp1), bb = max(sp0, sp1);
        int triu = aa * S - (aa * (aa - 1)) / 2 + (bb - aa);

#pragma unroll
        for (int s = 0; s < SUB; ++s)
            atomicAdd(&row[s * NPAIRS + triu], pf[s >> 2] * f1[s & 3]);
    }
    __syncthreads();

    float* o = out + (size_t)a * AEV + RAD_W;
#pragma unroll
    for (int q = 0; q < ANG_W / 64; ++q) {
        int kk = q * 64 + lane;
        int triu = kk >> 5, s = kk & 31;
        o[kk] = row[s * NPAIRS + triu];
    }
}

// ---------------- launch ----------------

extern "C" void kernel_launch(void* const* d_in, const int* in_sizes, int n_in,
                              void* d_out, int out_size, void* d_ws, size_t ws_size,
                              hipStream_t stream) {
    const int*   atom_index   = (const int*)d_in[0];
    const int*   pair_indices = (const int*)d_in[1];
    const float* d_ij         = (const float*)d_in[2];
    const float* r_ij         = (const float*)d_in[3];
    const int*   central      = (const int*)d_in[4];
    const int*   pidx12       = (const int*)d_in[5];
    const int*   sign12       = (const int*)d_in[6];
    float*       out          = (float*)d_out;
    const int    T            = in_sizes[4];

    // preferred: packed pairs + fixed-capacity bins + triple offsets + v8 fused
    float4*   packed = (float4*)d_ws;
    unsigned* binsP  = (unsigned*)(packed + PA);
    int*      bcntP  = (int*)(binsP + (size_t)NATOMS * CAP);
    int*      toffP  = bcntP + NATOMS;
    size_t need_packed = (size_t)PA * 16 + (size_t)NATOMS * CAP * 4
                       + (size_t)NATOMS * 4 + (size_t)(NATOMS + 1) * 4;

    // fallback: CSR
    unsigned* ent = (unsigned*)d_ws;
    int* ints = (int*)(ent + 2 * (size_t)P);
    int* cnt        = ints;
    int* off        = cnt + NATOMS;
    int* cur        = off + NATOMS + 1;
    int* chunk      = cur + NATOMS;
    int* chunk_excl = chunk + NCHUNK;
    size_t need_csr = (char*)(chunk_excl + NCHUNK + 1) - (char*)d_ws;

    if (ws_size >= need_packed) {
        hipMemsetAsync(bcntP, 0, (size_t)NATOMS * 4, stream);
        if (T <= 0) {
            hipMemsetAsync(toffP, 0, (size_t)(NATOMS + 1) * 4, stream);
        }
        int work = (P > T) ? P : T;
        scatter_binned_kernel<<<(work + 255) / 256, 256, 0, stream>>>(
            pair_indices, atom_index, d_ij, r_ij, bcntP, binsP, packed,
            central, (T > 0) ? toffP : nullptr, T);
        fused_rows2_kernel<<<NATOMS / APB, 256, 0, stream>>>(
            bcntP, binsP, pidx12, sign12, toffP, packed, out, T);
    } else if (ws_size >= need_csr) {
        zero_cnt_kernel<<<(NATOMS + 255) / 256, 256, 0, stream>>>(cnt);
        hist_kernel<<<(P + 255) / 256, 256, 0, stream>>>(pair_indices, cnt);
        scan1_kernel<<<NCHUNK, 256, 0, stream>>>(cnt, off, chunk);
        scan2_kernel<<<1, 64, 0, stream>>>(chunk, chunk_excl);
        scan3_kernel<<<(NATOMS + 255) / 256, 256, 0, stream>>>(off, cur, chunk_excl);
        scatter_csr_kernel<<<(P + 255) / 256, 256, 0, stream>>>(pair_indices, atom_index,
                                                                d_ij, cur, ent);
        radial_rows_csr_kernel<<<NATOMS, 64, 0, stream>>>(off, ent, out);
        angular_rows_kernel<<<NATOMS, 64, 0, stream>>>(atom_index, pair_indices, r_ij,
                                                       central, pidx12, sign12, out, T);
    } else {
        zero_radial_kernel<<<((long long)NATOMS * RAD_W + 255) / 256, 256, 0, stream>>>(out);
        radial_atomic_kernel<<<(P + 255) / 256, 256, 0, stream>>>(atom_index, pair_indices,
                                                                  d_ij, out);
        angular_rows_kernel<<<NATOMS, 64, 0, stream>>>(atom_index, pair_indices, r_ij,
                                                       central, pidx12, sign12, out, T);
    }
}